// Round 1
// baseline (253.736 us; speedup 1.0000x reference)
//
#include <hip/hip_runtime.h>

constexpr int NB = 2;
constexpr int NC = 64;
constexpr int NH = 192;
constexpr int NW = 192;
constexpr int NK = 7;
constexpr int NPAD = 3;
constexpr int NHW = NH * NW;          // 36864
constexpr int NPIX = NB * NHW;        // 73728
constexpr float EPS = 1e-6f;

// ---------------------------------------------------------------------------
// Kernel 1: per-pixel layernorm over C + 1x1 conv (65 in -> 128 out) -> q, k
// q/k stored channel-first: buf[(b*NC+o)*NHW + hw]
// ---------------------------------------------------------------------------
__global__ __launch_bounds__(256) void qk_kernel(
    const float* __restrict__ g, const float* __restrict__ cd,
    const float* __restrict__ mask,
    const float* __restrict__ ln_w, const float* __restrict__ ln_b,
    const float* __restrict__ conv_w, const float* __restrict__ conv_b,
    float* __restrict__ qbuf, float* __restrict__ kbuf)
{
    int p = blockIdx.x * 256 + threadIdx.x;   // [0, NPIX)
    int b = p / NHW;
    int hw = p - b * NHW;

    const float* gp = g + (size_t)b * NC * NHW + hw;

    float z[NC + 1];
    float sum = 0.f, sumsq = 0.f;
#pragma unroll
    for (int c = 0; c < NC; ++c) {
        float v = gp[c * NHW];
        z[c] = v;
        sum += v;
        sumsq += v * v;
    }
    float mu = sum * (1.f / NC);
    float var = sumsq * (1.f / NC) - mu * mu;
    float rstd = rsqrtf(var + EPS);
#pragma unroll
    for (int c = 0; c < NC; ++c)
        z[c] = (z[c] - mu) * rstd * ln_w[c] + ln_b[c];
    z[NC] = cd[p];

    float m = mask[p];

    float* qo = qbuf + (size_t)b * NC * NHW + hw;
    float* ko = kbuf + (size_t)b * NC * NHW + hw;

    for (int o = 0; o < NC; ++o) {
        const float* wq = conv_w + o * (NC + 1);          // uniform -> s_load
        const float* wk = conv_w + (o + NC) * (NC + 1);
        float accq = conv_b[o];
        float acck = conv_b[o + NC];
#pragma unroll
        for (int c = 0; c < NC + 1; ++c) {
            accq += wq[c] * z[c];
            acck += wk[c] * z[c];
        }
        qo[o * NHW] = accq;
        ko[o * NHW] = acck * m;
    }
}

// ---------------------------------------------------------------------------
// Kernel 2: 7x7 windowed attention + softmax + weighted cd/mask aggregation
// One thread per pixel.
// ---------------------------------------------------------------------------
__global__ __launch_bounds__(256) void attn_kernel(
    const float* __restrict__ qbuf, const float* __restrict__ kbuf,
    const float* __restrict__ cd, const float* __restrict__ sd,
    const float* __restrict__ mask, const float* __restrict__ rpb,
    float* __restrict__ out_cd, float* __restrict__ out_mask)
{
    int p = blockIdx.x * 256 + threadIdx.x;   // [0, NPIX)
    int b = p / NHW;
    int hw = p - b * NHW;
    int h = hw / NW;
    int w = hw - h * NW;

    int rs = min(max(h - NPAD, 0), NH - NK);  // window top row
    int cs = min(max(w - NPAD, 0), NW - NK);  // window left col

    float attn[NK * NK];
#pragma unroll
    for (int n = 0; n < NK * NK; ++n) attn[n] = 0.f;

    const float* qp = qbuf + (size_t)b * NC * NHW + hw;
    const float* kp = kbuf + (size_t)b * NC * NHW + rs * NW + cs;

    for (int c = 0; c < NC; ++c) {
        float qc = qp[c * NHW];
        const float* kc = kp + c * NHW;
#pragma unroll
        for (int i = 0; i < NK; ++i) {
#pragma unroll
            for (int j = 0; j < NK; ++j) {
                attn[i * NK + j] += qc * kc[i * NW + j];
            }
        }
    }

    // relative position bias
    int pr = (NK - 1) - (h - rs);
    int pc = (NK - 1) - (w - cs);
#pragma unroll
    for (int i = 0; i < NK; ++i) {
#pragma unroll
        for (int j = 0; j < NK; ++j) {
            attn[i * NK + j] += rpb[(pr + i) * (2 * NK - 1) + (pc + j)];
        }
    }

    // softmax over 49
    float mx = -1e30f;
#pragma unroll
    for (int n = 0; n < NK * NK; ++n) mx = fmaxf(mx, attn[n]);
    float s = 0.f;
#pragma unroll
    for (int n = 0; n < NK * NK; ++n) {
        attn[n] = __expf(attn[n] - mx);
        s += attn[n];
    }
    float inv = 1.f / s;

    // weighted sums over window (unnormalized, normalize at end)
    const float* cdp = cd + (size_t)b * NHW + rs * NW + cs;
    const float* mp  = mask + (size_t)b * NHW + rs * NW + cs;
    float oc = 0.f, om = 0.f;
#pragma unroll
    for (int i = 0; i < NK; ++i) {
#pragma unroll
        for (int j = 0; j < NK; ++j) {
            float a = attn[i * NK + j];
            oc += a * cdp[i * NW + j];
            om += a * mp[i * NW + j];
        }
    }
    oc *= inv;
    om *= inv;

    float mc  = mask[p];
    float cdc = cd[p];
    float sdc = sd[p];

    float co = oc * mc + cdc * (1.f - mc);
    float mo = om;
    if (sdc > 0.f) { co = sdc; mo = mc; }

    out_cd[p] = co;
    out_mask[p] = mo;
}

extern "C" void kernel_launch(void* const* d_in, const int* in_sizes, int n_in,
                              void* d_out, int out_size, void* d_ws, size_t ws_size,
                              hipStream_t stream) {
    const float* g      = (const float*)d_in[0];
    const float* cd     = (const float*)d_in[1];
    const float* sd     = (const float*)d_in[2];
    const float* mask   = (const float*)d_in[3];
    const float* ln_w   = (const float*)d_in[4];
    const float* ln_b   = (const float*)d_in[5];
    const float* conv_w = (const float*)d_in[6];
    const float* conv_b = (const float*)d_in[7];
    const float* rpb    = (const float*)d_in[8];

    float* out = (float*)d_out;                 // [cd_out | mask_out]
    float* qbuf = (float*)d_ws;                 // NB*NC*NHW floats
    float* kbuf = qbuf + (size_t)NB * NC * NHW; // NB*NC*NHW floats

    dim3 block(256);
    dim3 grid(NPIX / 256);   // 288 blocks

    qk_kernel<<<grid, block, 0, stream>>>(g, cd, mask, ln_w, ln_b, conv_w,
                                          conv_b, qbuf, kbuf);
    attn_kernel<<<grid, block, 0, stream>>>(qbuf, kbuf, cd, sd, mask, rpb,
                                            out, out + NPIX);
}

// Round 2
// 228.365 us; speedup vs baseline: 1.1111x; 1.1111x over previous
//
#include <hip/hip_runtime.h>

constexpr int NB = 2;
constexpr int NC = 64;
constexpr int NH = 192;
constexpr int NW = 192;
constexpr int NK = 7;
constexpr int NPAD = 3;
constexpr int NHW = NH * NW;          // 36864
constexpr int NPIX = NB * NHW;        // 73728
constexpr float EPS = 1e-6f;

// ---------------------------------------------------------------------------
// Kernel 1: per-pixel layernorm over C + 1x1 conv (65 in -> 128 out) -> q, k
// o-loop split x4 across blocks: blockIdx.x & 3 selects the 16-o chunk.
// Layernorm recomputed per chunk (cheap vs 2080 FMAs of matvec work).
// q/k stored channel-first: buf[(b*NC+o)*NHW + hw]
// ---------------------------------------------------------------------------
__global__ __launch_bounds__(256) void qk_kernel(
    const float* __restrict__ g, const float* __restrict__ cd,
    const float* __restrict__ mask,
    const float* __restrict__ ln_w, const float* __restrict__ ln_b,
    const float* __restrict__ conv_w, const float* __restrict__ conv_b,
    float* __restrict__ qbuf, float* __restrict__ kbuf)
{
    int oc = blockIdx.x & 3;                       // uniform per block
    int p = (blockIdx.x >> 2) * 256 + threadIdx.x; // [0, NPIX)
    int b = p / NHW;
    int hw = p - b * NHW;

    const float* gp = g + (size_t)b * NC * NHW + hw;

    float z[NC + 1];
    float sum = 0.f, sumsq = 0.f;
#pragma unroll
    for (int c = 0; c < NC; ++c) {
        float v = gp[c * NHW];
        z[c] = v;
        sum += v;
        sumsq += v * v;
    }
    float mu = sum * (1.f / NC);
    float var = sumsq * (1.f / NC) - mu * mu;
    float rstd = rsqrtf(var + EPS);
#pragma unroll
    for (int c = 0; c < NC; ++c)
        z[c] = (z[c] - mu) * rstd * ln_w[c] + ln_b[c];
    z[NC] = cd[p];

    float m = mask[p];

    float* qo = qbuf + (size_t)b * NC * NHW + hw;
    float* ko = kbuf + (size_t)b * NC * NHW + hw;

    for (int oo = 0; oo < 16; ++oo) {
        int o = oc * 16 + oo;                      // uniform per block
        const float* wq = conv_w + o * (NC + 1);   // uniform -> s_load
        const float* wk = conv_w + (o + NC) * (NC + 1);
        float accq = conv_b[o];
        float acck = conv_b[o + NC];
#pragma unroll
        for (int c = 0; c < NC + 1; ++c) {
            accq += wq[c] * z[c];
            acck += wk[c] * z[c];
        }
        qo[o * NHW] = accq;
        ko[o * NHW] = acck * m;
    }
}

// ---------------------------------------------------------------------------
// Kernel 2: 7x7 windowed attention + softmax + weighted cd/mask aggregation
// Channel reduction split x4 within the wave:
//   lane = 16*cq + px; quarter-wave handles 16 consecutive pixels, 16 channels
//   partial logits combined with 2 shfl_xor butterfly rounds (xor 16, 32).
// ---------------------------------------------------------------------------
__global__ __launch_bounds__(256) void attn_kernel(
    const float* __restrict__ qbuf, const float* __restrict__ kbuf,
    const float* __restrict__ cd, const float* __restrict__ sd,
    const float* __restrict__ mask, const float* __restrict__ rpb,
    float* __restrict__ out_cd, float* __restrict__ out_mask)
{
    int tid = threadIdx.x;
    int lane = tid & 63;
    int wave = tid >> 6;
    int px = lane & 15;       // pixel within quarter-group
    int cq = lane >> 4;       // channel quarter [0,4)

    int p = blockIdx.x * 64 + wave * 16 + px;   // [0, NPIX)
    int b = p / NHW;
    int hw = p - b * NHW;
    int h = hw / NW;
    int w = hw - h * NW;

    int rs = min(max(h - NPAD, 0), NH - NK);  // window top row
    int cs = min(max(w - NPAD, 0), NW - NK);  // window left col

    float attn[NK * NK];
#pragma unroll
    for (int n = 0; n < NK * NK; ++n) attn[n] = 0.f;

    const float* qp = qbuf + (size_t)b * NC * NHW + (size_t)cq * 16 * NHW + hw;
    const float* kp = kbuf + (size_t)b * NC * NHW + (size_t)cq * 16 * NHW
                      + rs * NW + cs;

    for (int c = 0; c < 16; ++c) {
        float qc = qp[c * NHW];
        const float* kc = kp + c * NHW;
#pragma unroll
        for (int i = 0; i < NK; ++i) {
#pragma unroll
            for (int j = 0; j < NK; ++j) {
                attn[i * NK + j] += qc * kc[i * NW + j];
            }
        }
    }

    // butterfly-combine the 4 channel quarters: all lanes end with full sum
#pragma unroll
    for (int n = 0; n < NK * NK; ++n) {
        attn[n] += __shfl_xor(attn[n], 16);
        attn[n] += __shfl_xor(attn[n], 32);
    }

    // relative position bias
    int pr = (NK - 1) - (h - rs);
    int pc = (NK - 1) - (w - cs);
#pragma unroll
    for (int i = 0; i < NK; ++i) {
#pragma unroll
        for (int j = 0; j < NK; ++j) {
            attn[i * NK + j] += rpb[(pr + i) * (2 * NK - 1) + (pc + j)];
        }
    }

    // softmax over 49 (redundant across quarters; no divergence)
    float mx = -1e30f;
#pragma unroll
    for (int n = 0; n < NK * NK; ++n) mx = fmaxf(mx, attn[n]);
    float s = 0.f;
#pragma unroll
    for (int n = 0; n < NK * NK; ++n) {
        attn[n] = __expf(attn[n] - mx);
        s += attn[n];
    }
    float inv = 1.f / s;

    // weighted sums over window
    const float* cdp = cd + (size_t)b * NHW + rs * NW + cs;
    const float* mp  = mask + (size_t)b * NHW + rs * NW + cs;
    float ocv = 0.f, om = 0.f;
#pragma unroll
    for (int i = 0; i < NK; ++i) {
#pragma unroll
        for (int j = 0; j < NK; ++j) {
            float a = attn[i * NK + j];
            ocv += a * cdp[i * NW + j];
            om += a * mp[i * NW + j];
        }
    }
    ocv *= inv;
    om *= inv;

    float mc  = mask[p];
    float cdc = cd[p];
    float sdc = sd[p];

    float co = ocv * mc + cdc * (1.f - mc);
    float mo = om;
    if (sdc > 0.f) { co = sdc; mo = mc; }

    if (cq == 0) {
        out_cd[p] = co;
        out_mask[p] = mo;
    }
}

extern "C" void kernel_launch(void* const* d_in, const int* in_sizes, int n_in,
                              void* d_out, int out_size, void* d_ws, size_t ws_size,
                              hipStream_t stream) {
    const float* g      = (const float*)d_in[0];
    const float* cd     = (const float*)d_in[1];
    const float* sd     = (const float*)d_in[2];
    const float* mask   = (const float*)d_in[3];
    const float* ln_w   = (const float*)d_in[4];
    const float* ln_b   = (const float*)d_in[5];
    const float* conv_w = (const float*)d_in[6];
    const float* conv_b = (const float*)d_in[7];
    const float* rpb    = (const float*)d_in[8];

    float* out = (float*)d_out;                 // [cd_out | mask_out]
    float* qbuf = (float*)d_ws;                 // NB*NC*NHW floats
    float* kbuf = qbuf + (size_t)NB * NC * NHW; // NB*NC*NHW floats

    dim3 block(256);

    qk_kernel<<<dim3((NPIX / 256) * 4), block, 0, stream>>>(
        g, cd, mask, ln_w, ln_b, conv_w, conv_b, qbuf, kbuf);
    attn_kernel<<<dim3(NPIX / 64), block, 0, stream>>>(
        qbuf, kbuf, cd, sd, mask, rpb, out, out + NPIX);
}

// Round 3
// 144.945 us; speedup vs baseline: 1.7506x; 1.5755x over previous
//
#include <hip/hip_runtime.h>

constexpr int NB = 2;
constexpr int NC = 64;
constexpr int NH = 192;
constexpr int NW = 192;
constexpr int NK = 7;
constexpr int NHW = NH * NW;          // 36864
constexpr int NPIX = NB * NHW;        // 73728
constexpr float EPS = 1e-6f;

// ---------------------------------------------------------------------------
// Kernel 1: layernorm + 1x1 conv as LDS-tiled GEMM.
// out[128][NPIX] = W[128][65] x Z[65][NPIX];  block = 128 pixels.
// Z[65][128] in LDS (phase A), W chunked [33][128] in LDS, 8x8 register tiles.
// ---------------------------------------------------------------------------
__global__ __launch_bounds__(256) void qk_gemm(
    const float* __restrict__ g, const float* __restrict__ cd,
    const float* __restrict__ mask,
    const float* __restrict__ ln_w, const float* __restrict__ ln_b,
    const float* __restrict__ conv_w, const float* __restrict__ conv_b,
    float* __restrict__ qbuf, float* __restrict__ kbuf)
{
    __shared__ float Z[65][128];     // 33.3 KB
    __shared__ float WTc[33][128];   // 16.9 KB

    int tid = threadIdx.x;
    int p0 = blockIdx.x * 128;
    int b  = p0 / NHW;
    int hw0 = p0 - b * NHW;

    // ---- Phase A: layernorm -> Z (pairs of lanes split the 64 channels) ----
    int px = tid >> 1;
    int hf = tid & 1;
    const float* gp = g + (size_t)(b * NC + hf * 32) * NHW + (hw0 + px);
    float vals[32];
    float s = 0.f, sq = 0.f;
#pragma unroll
    for (int j = 0; j < 32; ++j) {
        float v = gp[(size_t)j * NHW];
        vals[j] = v; s += v; sq += v * v;
    }
    s  += __shfl_xor(s, 1);
    sq += __shfl_xor(sq, 1);
    float mu   = s * (1.f / 64.f);
    float rstd = rsqrtf(sq * (1.f / 64.f) - mu * mu + EPS);
#pragma unroll
    for (int j = 0; j < 32; ++j) {
        int c = hf * 32 + j;
        Z[c][px] = (vals[j] - mu) * rstd * ln_w[c] + ln_b[c];
    }
    if (hf) Z[64][px] = cd[p0 + px];

    // ---- Phase B: GEMM with 8x8 register tiles ----
    int og = tid >> 4;    // 16 groups x 8 outputs
    int pg = tid & 15;    // 16 groups x 8 pixels
    float acc[8][8];
#pragma unroll
    for (int oi = 0; oi < 8; ++oi)
#pragma unroll
        for (int pj = 0; pj < 8; ++pj) acc[oi][pj] = 0.f;

    for (int cc = 0; cc < 65; cc += 33) {
        int nr = (65 - cc < 33) ? (65 - cc) : 33;
        __syncthreads();             // protect WTc reuse + (first pass) Z writes
        if (tid < 128) {
            int o = tid;
            for (int r = 0; r < nr; ++r)
                WTc[r][o] = conv_w[o * 65 + cc + r];
        }
        __syncthreads();
        for (int r = 0; r < nr; ++r) {
            float4 w0 = *(const float4*)&WTc[r][8 * og];
            float4 w1 = *(const float4*)&WTc[r][8 * og + 4];
            float4 z0 = *(const float4*)&Z[cc + r][8 * pg];
            float4 z1 = *(const float4*)&Z[cc + r][8 * pg + 4];
            float w8[8] = {w0.x, w0.y, w0.z, w0.w, w1.x, w1.y, w1.z, w1.w};
            float z8[8] = {z0.x, z0.y, z0.z, z0.w, z1.x, z1.y, z1.z, z1.w};
#pragma unroll
            for (int oi = 0; oi < 8; ++oi)
#pragma unroll
                for (int pj = 0; pj < 8; ++pj)
                    acc[oi][pj] = fmaf(w8[oi], z8[pj], acc[oi][pj]);
        }
    }

    // ---- epilogue: bias, mask (k half), store ----
    int o0  = og * 8;
    int pxb = pg * 8;
    float4 ba = *(const float4*)&conv_b[o0];
    float4 bb = *(const float4*)&conv_b[o0 + 4];
    float bia[8] = {ba.x, ba.y, ba.z, ba.w, bb.x, bb.y, bb.z, bb.w};
    bool isq = (o0 < 64);
    float m8[8];
    if (!isq) {
        float4 ma = *(const float4*)&mask[p0 + pxb];
        float4 mc = *(const float4*)&mask[p0 + pxb + 4];
        m8[0]=ma.x; m8[1]=ma.y; m8[2]=ma.z; m8[3]=ma.w;
        m8[4]=mc.x; m8[5]=mc.y; m8[6]=mc.z; m8[7]=mc.w;
    }
    float* base = isq ? (qbuf + (size_t)(b * NC + o0) * NHW + hw0 + pxb)
                      : (kbuf + (size_t)(b * NC + o0 - 64) * NHW + hw0 + pxb);
#pragma unroll
    for (int oi = 0; oi < 8; ++oi) {
        float v[8];
#pragma unroll
        for (int pj = 0; pj < 8; ++pj) {
            float t = acc[oi][pj] + bia[oi];
            v[pj] = isq ? t : t * m8[pj];
        }
        float* dst = base + (size_t)oi * NHW;
        *(float4*)&dst[0] = make_float4(v[0], v[1], v[2], v[3]);
        *(float4*)&dst[4] = make_float4(v[4], v[5], v[6], v[7]);
    }
}

// ---------------------------------------------------------------------------
// Kernel 2: 7x7 windowed attention, 16x16 pixel tile per block.
// 2 px/thread, channel reduction split x2 across block halves (each half owns
// its own single-buffered 22x23 LDS k-tile, prefetching c+1 into registers
// during compute(c)). Partial logits combined via LDS exchange.
// ---------------------------------------------------------------------------
__global__ __launch_bounds__(256) void attn_tile(
    const float* __restrict__ qbuf, const float* __restrict__ kbuf,
    const float* __restrict__ cd, const float* __restrict__ sd,
    const float* __restrict__ mask, const float* __restrict__ rpb,
    float* __restrict__ out_cd, float* __restrict__ out_mask)
{
    __shared__ float kst[2][2][22 * 23];   // [half][buf] 8.1 KB
    __shared__ float cdt[22 * 23];
    __shared__ float mt [22 * 23];
    __shared__ float rpbt[169];
    __shared__ float xbuf[128][98];        // 49 KB logit exchange

    int tid  = threadIdx.x;
    int idx  = tid & 127;
    int half = tid >> 7;

    int bw = blockIdx.x % 12;
    int t2 = blockIdx.x / 12;
    int bh = t2 % 12;
    int b  = t2 / 12;
    int w0 = bw * 16, h0 = bh * 16;

    int tx = idx & 7, ty = idx >> 3;
    int h  = h0 + ty;
    int wA = w0 + 2 * tx;
    int rs  = min(max(h - 3, 0), NH - NK);
    int cs0 = min(max(wA - 3, 0), NW - NK);
    int cs1 = min(max(wA - 2, 0), NW - NK);
    int d1  = cs1 - cs0;                       // 0 or 1
    int rb  = (rs - h0 + 3) * 23 + (cs0 - w0 + 3);

    // staging slot precompute (4 rounds of 128 threads for 484 elems)
    int soff[4], slds[4], sact[4];
#pragma unroll
    for (int sI = 0; sI < 4; ++sI) {
        int e = idx + 128 * sI;
        int r = e / 22, x = e - r * 22;
        int gr = min(max(h0 - 3 + r, 0), NH - 1);
        int gc = min(max(w0 - 3 + x, 0), NW - 1);
        soff[sI] = gr * NW + gc;
        slds[sI] = r * 23 + x;
        sact[sI] = (e < 484);
    }

    // stage cd / mask / rpb once
    const float* cdb = cd   + (size_t)b * NHW;
    const float* msb = mask + (size_t)b * NHW;
    for (int e = tid; e < 484; e += 256) {
        int r = e / 22, x = e - r * 22;
        int gr = min(max(h0 - 3 + r, 0), NH - 1);
        int gc = min(max(w0 - 3 + x, 0), NW - 1);
        cdt[r * 23 + x] = cdb[gr * NW + gc];
        mt [r * 23 + x] = msb[gr * NW + gc];
    }
    if (tid < 169) rpbt[tid] = rpb[tid];

    const float* kb = kbuf + (size_t)(b * NC + half * 32) * NHW;
    const float* qb = qbuf + (size_t)(b * NC + half * 32) * NHW + (h * NW + wA);

    float at0[49], at1[49];
#pragma unroll
    for (int n = 0; n < 49; ++n) { at0[n] = 0.f; at1[n] = 0.f; }

    // prefetch + stage channel 0 of this half
    float st[4];
#pragma unroll
    for (int sI = 0; sI < 4; ++sI)
        st[sI] = sact[sI] ? kb[soff[sI]] : 0.f;
    float* myk0 = kst[half][0];
    float* myk1 = kst[half][1];
#pragma unroll
    for (int sI = 0; sI < 4; ++sI)
        if (sact[sI]) myk0[slds[sI]] = st[sI];

    for (int i = 0; i < 32; ++i) {
        __syncthreads();
        if (i + 1 < 32) {
            const float* kb2 = kb + (size_t)(i + 1) * NHW;
#pragma unroll
            for (int sI = 0; sI < 4; ++sI)
                st[sI] = sact[sI] ? kb2[soff[sI]] : 0.f;
        }
        float2 q2 = *(const float2*)(qb + (size_t)i * NHW);
        const float* kt = ((i & 1) ? myk1 : myk0) + rb;
#pragma unroll
        for (int r = 0; r < 7; ++r) {
            float kr[8];
#pragma unroll
            for (int j = 0; j < 8; ++j) kr[j] = kt[r * 23 + j];
#pragma unroll
            for (int j = 0; j < 7; ++j) {
                float kA = kr[j];
                float kB = d1 ? kr[j + 1] : kr[j];
                at0[r * 7 + j] = fmaf(q2.x, kA, at0[r * 7 + j]);
                at1[r * 7 + j] = fmaf(q2.y, kB, at1[r * 7 + j]);
            }
        }
        if (i + 1 < 32) {
            float* nk = (i & 1) ? myk0 : myk1;
#pragma unroll
            for (int sI = 0; sI < 4; ++sI)
                if (sact[sI]) nk[slds[sI]] = st[sI];
        }
    }

    // ---- combine the two channel halves + bias ----
    float* xr = xbuf[idx];
    __syncthreads();
    if (half == 1) {
#pragma unroll
        for (int n = 0; n < 49; ++n)
            *(float2*)&xr[2 * n] = make_float2(at0[n], at1[n]);
    }
    __syncthreads();
    int pr  = 6 - (h - rs);
    int pc0 = 6 - (wA - cs0);
    int pc1 = 6 - (wA + 1 - cs1);
    if (half == 0) {
#pragma unroll
        for (int n = 0; n < 49; ++n) {
            float2 v = *(const float2*)&xr[2 * n];
            at0[n] += v.x; at1[n] += v.y;
        }
#pragma unroll
        for (int r = 0; r < 7; ++r)
#pragma unroll
            for (int j = 0; j < 7; ++j) {
                at0[r * 7 + j] += rpbt[(pr + r) * 13 + pc0 + j];
                at1[r * 7 + j] += rpbt[(pr + r) * 13 + pc1 + j];
            }
#pragma unroll
        for (int n = 0; n < 49; ++n)
            *(float2*)&xr[2 * n] = make_float2(at0[n], at1[n]);
    }
    __syncthreads();
    if (half == 1) {
#pragma unroll
        for (int n = 0; n < 49; ++n) {
            float2 v = *(const float2*)&xr[2 * n];
            at0[n] = v.x; at1[n] = v.y;
        }
    }

    // ---- softmax (both halves, both pixels) ----
    float mx0 = -1e30f, mx1 = -1e30f;
#pragma unroll
    for (int n = 0; n < 49; ++n) {
        mx0 = fmaxf(mx0, at0[n]); mx1 = fmaxf(mx1, at1[n]);
    }
    float sm0 = 0.f, sm1 = 0.f;
#pragma unroll
    for (int n = 0; n < 49; ++n) {
        at0[n] = __expf(at0[n] - mx0); sm0 += at0[n];
        at1[n] = __expf(at1[n] - mx1); sm1 += at1[n];
    }

    // ---- aggregate: half 0 -> cd, half 1 -> mask ----
    const float* vt = half ? mt : cdt;
    float s0 = 0.f, s1 = 0.f;
#pragma unroll
    for (int r = 0; r < 7; ++r) {
        float vr[8];
#pragma unroll
        for (int j = 0; j < 8; ++j) vr[j] = vt[rb + r * 23 + j];
#pragma unroll
        for (int j = 0; j < 7; ++j) {
            float vA = vr[j];
            float vB = d1 ? vr[j + 1] : vr[j];
            s0 = fmaf(at0[r * 7 + j], vA, s0);
            s1 = fmaf(at1[r * 7 + j], vB, s1);
        }
    }
    s0 /= sm0; s1 /= sm1;

    int cidx = (ty + 3) * 23 + (2 * tx + 3);
    float mc0 = mt[cidx], mc1 = mt[cidx + 1];
    int p = b * NHW + h * NW + wA;
    float2 sd2 = *(const float2*)&sd[p];
    if (half == 0) {
        float cdc0 = cdt[cidx], cdc1 = cdt[cidx + 1];
        float c0 = s0 * mc0 + cdc0 * (1.f - mc0);
        float c1 = s1 * mc1 + cdc1 * (1.f - mc1);
        if (sd2.x > 0.f) c0 = sd2.x;
        if (sd2.y > 0.f) c1 = sd2.y;
        *(float2*)&out_cd[p] = make_float2(c0, c1);
    } else {
        float m0 = (sd2.x > 0.f) ? mc0 : s0;
        float m1 = (sd2.y > 0.f) ? mc1 : s1;
        *(float2*)&out_mask[p] = make_float2(m0, m1);
    }
}

extern "C" void kernel_launch(void* const* d_in, const int* in_sizes, int n_in,
                              void* d_out, int out_size, void* d_ws, size_t ws_size,
                              hipStream_t stream) {
    const float* g      = (const float*)d_in[0];
    const float* cd     = (const float*)d_in[1];
    const float* sd     = (const float*)d_in[2];
    const float* mask   = (const float*)d_in[3];
    const float* ln_w   = (const float*)d_in[4];
    const float* ln_b   = (const float*)d_in[5];
    const float* conv_w = (const float*)d_in[6];
    const float* conv_b = (const float*)d_in[7];
    const float* rpb    = (const float*)d_in[8];

    float* out  = (float*)d_out;                 // [cd_out | mask_out]
    float* qbuf = (float*)d_ws;                  // NB*NC*NHW floats
    float* kbuf = qbuf + (size_t)NB * NC * NHW;  // NB*NC*NHW floats

    qk_gemm<<<dim3(NPIX / 128), dim3(256), 0, stream>>>(
        g, cd, mask, ln_w, ln_b, conv_w, conv_b, qbuf, kbuf);
    attn_tile<<<dim3(NB * 144), dim3(256), 0, stream>>>(
        qbuf, kbuf, cd, sd, mask, rpb, out, out + NPIX);
}

// Round 4
// 140.690 us; speedup vs baseline: 1.8035x; 1.0302x over previous
//
#include <hip/hip_runtime.h>

constexpr int NB = 2;
constexpr int NC = 64;
constexpr int NH = 192;
constexpr int NW = 192;
constexpr int NK = 7;
constexpr int NHW = NH * NW;          // 36864
constexpr int NPIX = NB * NHW;        // 73728
constexpr float EPS = 1e-6f;

// ---------------------------------------------------------------------------
// Kernel 1: layernorm + 1x1 conv as LDS-tiled GEMM.  (unchanged from R3)
// ---------------------------------------------------------------------------
__global__ __launch_bounds__(256) void qk_gemm(
    const float* __restrict__ g, const float* __restrict__ cd,
    const float* __restrict__ mask,
    const float* __restrict__ ln_w, const float* __restrict__ ln_b,
    const float* __restrict__ conv_w, const float* __restrict__ conv_b,
    float* __restrict__ qbuf, float* __restrict__ kbuf)
{
    __shared__ float Z[65][128];
    __shared__ float WTc[33][128];

    int tid = threadIdx.x;
    int p0 = blockIdx.x * 128;
    int b  = p0 / NHW;
    int hw0 = p0 - b * NHW;

    int px = tid >> 1;
    int hf = tid & 1;
    const float* gp = g + (size_t)(b * NC + hf * 32) * NHW + (hw0 + px);
    float vals[32];
    float s = 0.f, sq = 0.f;
#pragma unroll
    for (int j = 0; j < 32; ++j) {
        float v = gp[(size_t)j * NHW];
        vals[j] = v; s += v; sq += v * v;
    }
    s  += __shfl_xor(s, 1);
    sq += __shfl_xor(sq, 1);
    float mu   = s * (1.f / 64.f);
    float rstd = rsqrtf(sq * (1.f / 64.f) - mu * mu + EPS);
#pragma unroll
    for (int j = 0; j < 32; ++j) {
        int c = hf * 32 + j;
        Z[c][px] = (vals[j] - mu) * rstd * ln_w[c] + ln_b[c];
    }
    if (hf) Z[64][px] = cd[p0 + px];

    int og = tid >> 4;
    int pg = tid & 15;
    float acc[8][8];
#pragma unroll
    for (int oi = 0; oi < 8; ++oi)
#pragma unroll
        for (int pj = 0; pj < 8; ++pj) acc[oi][pj] = 0.f;

    for (int cc = 0; cc < 65; cc += 33) {
        int nr = (65 - cc < 33) ? (65 - cc) : 33;
        __syncthreads();
        if (tid < 128) {
            int o = tid;
            for (int r = 0; r < nr; ++r)
                WTc[r][o] = conv_w[o * 65 + cc + r];
        }
        __syncthreads();
        for (int r = 0; r < nr; ++r) {
            float4 w0 = *(const float4*)&WTc[r][8 * og];
            float4 w1 = *(const float4*)&WTc[r][8 * og + 4];
            float4 z0 = *(const float4*)&Z[cc + r][8 * pg];
            float4 z1 = *(const float4*)&Z[cc + r][8 * pg + 4];
            float w8[8] = {w0.x, w0.y, w0.z, w0.w, w1.x, w1.y, w1.z, w1.w};
            float z8[8] = {z0.x, z0.y, z0.z, z0.w, z1.x, z1.y, z1.z, z1.w};
#pragma unroll
            for (int oi = 0; oi < 8; ++oi)
#pragma unroll
                for (int pj = 0; pj < 8; ++pj)
                    acc[oi][pj] = fmaf(w8[oi], z8[pj], acc[oi][pj]);
        }
    }

    int o0  = og * 8;
    int pxb = pg * 8;
    float4 ba = *(const float4*)&conv_b[o0];
    float4 bb = *(const float4*)&conv_b[o0 + 4];
    float bia[8] = {ba.x, ba.y, ba.z, ba.w, bb.x, bb.y, bb.z, bb.w};
    bool isq = (o0 < 64);
    float m8[8];
    if (!isq) {
        float4 ma = *(const float4*)&mask[p0 + pxb];
        float4 mc = *(const float4*)&mask[p0 + pxb + 4];
        m8[0]=ma.x; m8[1]=ma.y; m8[2]=ma.z; m8[3]=ma.w;
        m8[4]=mc.x; m8[5]=mc.y; m8[6]=mc.z; m8[7]=mc.w;
    }
    float* base = isq ? (qbuf + (size_t)(b * NC + o0) * NHW + hw0 + pxb)
                      : (kbuf + (size_t)(b * NC + o0 - 64) * NHW + hw0 + pxb);
#pragma unroll
    for (int oi = 0; oi < 8; ++oi) {
        float v[8];
#pragma unroll
        for (int pj = 0; pj < 8; ++pj) {
            float t = acc[oi][pj] + bia[oi];
            v[pj] = isq ? t : t * m8[pj];
        }
        float* dst = base + (size_t)oi * NHW;
        *(float4*)&dst[0] = make_float4(v[0], v[1], v[2], v[3]);
        *(float4*)&dst[4] = make_float4(v[4], v[5], v[6], v[7]);
    }
}

// ---------------------------------------------------------------------------
// Kernel 2 (v4): 8x16 pixel tile, 576 blocks, 4 waves/block.
// wave g: rq=g&1 (row quad: 4 rows x 16 cols = 64 px, 1 px/lane),
//         half=g>>1 (32 channels). Private per-wave k-subtile (10 rows,
//         pitch 24), double-buffered, wave-synchronous: NO barriers in the
//         channel loop. Logits combined via xch[128][49] (stride 49 -> 2-way
//         bank aliasing = free). 3 barriers total.
// ---------------------------------------------------------------------------
__global__ __launch_bounds__(256) void attn_tile(
    const float* __restrict__ qbuf, const float* __restrict__ kbuf,
    const float* __restrict__ cd, const float* __restrict__ sd,
    const float* __restrict__ mask, const float* __restrict__ rpb,
    float* __restrict__ out_cd, float* __restrict__ out_mask)
{
    __shared__ float kst[4][2][10 * 24];   // 7.7 KB
    __shared__ float cdt[14 * 24];         // 1.3 KB
    __shared__ float mt [14 * 24];         // 1.3 KB
    __shared__ float rpbt[169];
    __shared__ float xch[128][49];         // 24.5 KB

    int tid  = threadIdx.x;
    int g    = tid >> 6;
    int lane = tid & 63;
    int rq   = g & 1;
    int half = g >> 1;
    int tx   = lane & 15;
    int tyw  = lane >> 4;

    int bw = blockIdx.x % 12;
    int t2 = blockIdx.x / 12;
    int bh = t2 % 24;
    int b  = t2 / 24;
    int w0 = bw * 16, h0 = bh * 8;
    int hr0 = h0 + rq * 4;

    int h = hr0 + tyw;
    int w = w0 + tx;
    int rs = min(max(h - 3, 0), NH - NK);
    int cs = min(max(w - 3, 0), NW - NK);
    int rb  = (rs - (hr0 - 3)) * 24 + (cs - (w0 - 3));   // wave-local tile
    int rbB = (rs - (h0  - 3)) * 24 + (cs - (w0 - 3));   // block-level tile

    // ---- block-level cd/mask/rpb staging (visible after first barrier) ----
    const float* cdb = cd   + (size_t)b * NHW;
    const float* msb = mask + (size_t)b * NHW;
    for (int e = tid; e < 308; e += 256) {
        int r = e / 22, c2 = e - r * 22;
        int gr = min(max(h0 - 3 + r, 0), NH - 1);
        int gc = min(max(w0 - 3 + c2, 0), NW - 1);
        cdt[r * 24 + c2] = cdb[gr * NW + gc];
        mt [r * 24 + c2] = msb[gr * NW + gc];
    }
    if (tid < 169) rpbt[tid] = rpb[tid];

    // ---- wave-local k staging slots: 220 elems (10x22), 4 rounds of 64 ----
    int soff[4], slds[4]; bool sact[4];
#pragma unroll
    for (int s = 0; s < 4; ++s) {
        int e = lane + 64 * s;
        int r = e / 22, c2 = e - r * 22;
        int gr = min(max(hr0 - 3 + r, 0), NH - 1);
        int gc = min(max(w0 - 3 + c2, 0), NW - 1);
        soff[s] = gr * NW + gc;
        slds[s] = r * 24 + c2;
        sact[s] = (e < 220);
    }

    const float* kb = kbuf + (size_t)(b * NC + half * 32) * NHW;
    const float* qb = qbuf + (size_t)(b * NC + half * 32) * NHW + h * NW + w;

    float at[49];
#pragma unroll
    for (int n = 0; n < 49; ++n) at[n] = 0.f;

    float st[4];
#pragma unroll
    for (int s = 0; s < 4; ++s) st[s] = sact[s] ? kb[soff[s]] : 0.f;
    float* k0 = kst[g][0];
    float* k1 = kst[g][1];
#pragma unroll
    for (int s = 0; s < 4; ++s) if (sact[s]) k0[slds[s]] = st[s];

    for (int i = 0; i < 32; ++i) {
        if (i + 1 < 32) {
            const float* kb2 = kb + (size_t)(i + 1) * NHW;
#pragma unroll
            for (int s = 0; s < 4; ++s) st[s] = sact[s] ? kb2[soff[s]] : 0.f;
        }
        float q = qb[(size_t)i * NHW];
        const float* kt = ((i & 1) ? k1 : k0) + rb;
#pragma unroll
        for (int r = 0; r < 7; ++r)
#pragma unroll
            for (int j = 0; j < 7; ++j)
                at[r * 7 + j] = fmaf(q, kt[r * 24 + j], at[r * 7 + j]);
        if (i + 1 < 32) {
            float* nk = (i & 1) ? k0 : k1;
#pragma unroll
            for (int s = 0; s < 4; ++s) if (sact[s]) nk[slds[s]] = st[s];
        }
    }

    // ---- combine the two channel halves + bias ----
    int pxid = (rq * 4 + tyw) * 16 + tx;   // 0..127
    __syncthreads();
    if (half == 1) {
#pragma unroll
        for (int n = 0; n < 49; ++n) xch[pxid][n] = at[n];
    }
    __syncthreads();
    int pr = 6 - (h - rs);
    int pc = 6 - (w - cs);
    if (half == 0) {
#pragma unroll
        for (int n = 0; n < 49; ++n) at[n] += xch[pxid][n];
#pragma unroll
        for (int r = 0; r < 7; ++r)
#pragma unroll
            for (int j = 0; j < 7; ++j)
                at[r * 7 + j] += rpbt[(pr + r) * 13 + pc + j];
#pragma unroll
        for (int n = 0; n < 49; ++n) xch[pxid][n] = at[n];
    }
    __syncthreads();
    if (half == 1) {
#pragma unroll
        for (int n = 0; n < 49; ++n) at[n] = xch[pxid][n];
    }

    // ---- softmax (both halves, same logits) ----
    float mx = -1e30f;
#pragma unroll
    for (int n = 0; n < 49; ++n) mx = fmaxf(mx, at[n]);
    float sm = 0.f;
#pragma unroll
    for (int n = 0; n < 49; ++n) {
        at[n] = __expf(at[n] - mx);
        sm += at[n];
    }

    // ---- aggregate: half 0 -> cd, half 1 -> mask ----
    const float* vt = (half ? mt : cdt) + rbB;
    float sv = 0.f;
#pragma unroll
    for (int r = 0; r < 7; ++r)
#pragma unroll
        for (int j = 0; j < 7; ++j)
            sv = fmaf(at[r * 7 + j], vt[r * 24 + j], sv);
    sv /= sm;

    int p = b * NHW + h * NW + w;
    float sdc = sd[p];
    int cidx = (rq * 4 + tyw + 3) * 24 + (tx + 3);
    float mc = mt[cidx];
    if (half == 0) {
        float cdc = cdt[cidx];
        float co = sv * mc + cdc * (1.f - mc);
        if (sdc > 0.f) co = sdc;
        out_cd[p] = co;
    } else {
        out_mask[p] = (sdc > 0.f) ? mc : sv;
    }
}

extern "C" void kernel_launch(void* const* d_in, const int* in_sizes, int n_in,
                              void* d_out, int out_size, void* d_ws, size_t ws_size,
                              hipStream_t stream) {
    const float* g      = (const float*)d_in[0];
    const float* cd     = (const float*)d_in[1];
    const float* sd     = (const float*)d_in[2];
    const float* mask   = (const float*)d_in[3];
    const float* ln_w   = (const float*)d_in[4];
    const float* ln_b   = (const float*)d_in[5];
    const float* conv_w = (const float*)d_in[6];
    const float* conv_b = (const float*)d_in[7];
    const float* rpb    = (const float*)d_in[8];

    float* out  = (float*)d_out;                 // [cd_out | mask_out]
    float* qbuf = (float*)d_ws;                  // NB*NC*NHW floats
    float* kbuf = qbuf + (size_t)NB * NC * NHW;  // NB*NC*NHW floats

    qk_gemm<<<dim3(NPIX / 128), dim3(256), 0, stream>>>(
        g, cd, mask, ln_w, ln_b, conv_w, conv_b, qbuf, kbuf);
    attn_tile<<<dim3(NB * 24 * 12), dim3(256), 0, stream>>>(
        qbuf, kbuf, cd, sd, mask, rpb, out, out + NPIX);
}